// Round 11
// baseline (341.339 us; speedup 1.0000x reference)
//
#include <hip/hip_runtime.h>
#include <hip/hip_bf16.h>
#include <stdint.h>
#include <stddef.h>

using bf16 = __hip_bfloat16;

typedef __attribute__((ext_vector_type(4))) float f32x4;
typedef __attribute__((ext_vector_type(8))) short bf16x8;
typedef __attribute__((ext_vector_type(4))) unsigned short u16x4;

#define K_DIM 4096
#define M_ROWS 8192
#define BM 256
#define BN 128
#define BK 32
#define NTT (K_DIM / BK)     // 128 K-tiles
#define MT2 (M_ROWS / BM)    // 32
#define NT2 (K_DIM / BN)     // 32

// ---------------------------------------------------------------------------
// Kernel 1: f32 -> bf16 conversion (vectorized, grid-stride)
// ---------------------------------------------------------------------------
__global__ void conv_bf16(const float* __restrict__ in, bf16* __restrict__ outb, int n4) {
  int idx = blockIdx.x * blockDim.x + threadIdx.x;
  int stride = gridDim.x * blockDim.x;
  for (int k = idx; k < n4; k += stride) {
    f32x4 v = ((const f32x4*)in)[k];
    bf16 tmp[4];
    tmp[0] = __float2bfloat16(v.x);
    tmp[1] = __float2bfloat16(v.y);
    tmp[2] = __float2bfloat16(v.z);
    tmp[3] = __float2bfloat16(v.w);
    ((u16x4*)outb)[k] = *(const u16x4*)tmp;
  }
}

// ---------------------------------------------------------------------------
// Kernel 2: build G^T in bf16 (verified round 1).
// ---------------------------------------------------------------------------
__global__ void build_gt(const float* __restrict__ core0, const float* __restrict__ core1,
                         bf16* __restrict__ GT) {
  int j = blockIdx.x >> 6;
  int i = blockIdx.x & 63;
  __shared__ float c0s[64][16];
  __shared__ float c1s[64][16];
  int t = threadIdx.x;
#pragma unroll
  for (int rep = 0; rep < 4; ++rep) {
    int idx = rep * 256 + t;
    int row = idx >> 4;
    int b = idx & 15;
    size_t base = ((size_t)(j * 64 + row) * 64 + i) * 16 + b;
    c1s[row][b] = core1[base];
    c0s[row][b] = core0[base];
  }
  __syncthreads();
  int x = t & 63;
  int ys = t >> 6;
  float r1[16];
#pragma unroll
  for (int b = 0; b < 16; ++b) r1[b] = c1s[x][b];
#pragma unroll
  for (int yy = 0; yy < 16; ++yy) {
    int y = ys * 16 + yy;
    float acc = 0.f;
#pragma unroll
    for (int b = 0; b < 16; ++b) acc += r1[b] * c0s[y][b];
    GT[((size_t)(y * 64 + i) << 12) + (size_t)(j * 64 + x)] = __float2bfloat16(acc);
  }
}

// ---------------------------------------------------------------------------
// Kernel 3: R9's verified 256x128/BK=32/4-wave geometry (layout, fragments,
// epilogue all refcheck'd, 0 conflicts) with the R9 failure fixed:
// TRIPLE-buffered LDS (72 KiB -> 2 blocks/CU) + DEPTH-2 prefetch + counted
// vmcnt(12) (retires exactly tile-t's 6 loads, issued 2 iters earlier -> no
// latency exposure; t+1/t+2 stay in flight). Cross-block TLP supplies the
// LDS<->MFMA overlap no single-block schedule achieved (R3-R10: 270-335us).
// ---------------------------------------------------------------------------
__device__ __forceinline__ void gload_lds16(const bf16* g, bf16* l) {
  __builtin_amdgcn_global_load_lds(
      (const __attribute__((address_space(1))) unsigned int*)(g),
      (__attribute__((address_space(3))) unsigned int*)(l),
      16, 0, 0);
}

#define BARRIER() __builtin_amdgcn_s_barrier()
#define SP1() __builtin_amdgcn_s_setprio(1)
#define SP0() __builtin_amdgcn_s_setprio(0)
#define VMCNT12() asm volatile("s_waitcnt vmcnt(12)" ::: "memory")
#define VMCNT6()  asm volatile("s_waitcnt vmcnt(6)" ::: "memory")
#define VMCNT0()  asm volatile("s_waitcnt vmcnt(0)" ::: "memory")

__global__ __launch_bounds__(256, 2)
void gemm_xg(const bf16* __restrict__ Xb, const bf16* __restrict__ GT,
             const float* __restrict__ bias, float* __restrict__ out) {
  // A: 256 rows -> 128 superrows x 64 (16 KiB); B: 128 rows -> 64 x 64 (8 KiB)
  __shared__ bf16 As[3][128 * 64];
  __shared__ bf16 Bs[3][64 * 64];

  // XCD-aware swizzle: nwg = 1024, divisible by 8
  int bid = blockIdx.x;
  int sb = (bid & 7) * (MT2 * NT2 / 8) + (bid >> 3);
  int bm = sb >> 5;          // 0..31
  int bn = sb & 31;          // 0..31

  int t = threadIdx.x;
  int lane = t & 63;
  int wid = t >> 6;          // 4 waves

  // ---- staging addressing (verbatim R9, refcheck'd) ----
  int ssr = t >> 3;                       // 0..31 superrow within a call
  int sslot = t & 7;                      // dest 16B slot (linear)
  int sp = sslot ^ (ssr & 7);             // source slot (inverse swizzle)
  int srowpar = sp >> 2;                  // source row parity
  int skofs = (sp & 3) * 8;               // source k offset
  const bf16* gA0 = Xb + ((size_t)(bm * BM + 2 * ssr + srowpar) * K_DIM) + skofs;
  const bf16* gB0 = GT + ((size_t)(bn * BN + 2 * ssr + srowpar) * K_DIM) + skofs;
  int ldst = ssr * 64 + sslot * 8;        // dest elem offset (linear 16B/thread)

  auto stage = [&](int buf, int kt) {
#pragma unroll
    for (int h = 0; h < 4; ++h)
      gload_lds16(gA0 + (size_t)(h * 64) * K_DIM + kt * BK,
                  &As[buf][h * 32 * 64 + ldst]);
#pragma unroll
    for (int h = 0; h < 2; ++h)
      gload_lds16(gB0 + (size_t)(h * 64) * K_DIM + kt * BK,
                  &Bs[buf][h * 32 * 64 + ldst]);
  };

  // ---- fragment addressing (verbatim R9, refcheck'd) ----
  int wm = wid >> 1;         // 0..1 (M half)
  int wn = wid & 1;          // 0..1 (N half)
  int lr = lane & 15;
  int g4 = lane >> 4;        // k-slot 0..3
  int lh = lr >> 1;
  int lp = lr & 1;
  int aslot = ((lp << 2) | g4) ^ lh;
  int aoff = (wm * 64 + lh) * 64 + aslot * 8;   // + mi*512
  int boff = (wn * 32 + lh) * 64 + aslot * 8;   // + ni*512

  f32x4 acc[8][4] = {};

  auto compute = [&](const bf16* Ac, const bf16* Bc) {
    bf16x8 af[8], bf4[4];
#pragma unroll
    for (int mi = 0; mi < 8; ++mi)
      af[mi] = *(const bf16x8*)&Ac[aoff + mi * 512];
#pragma unroll
    for (int ni = 0; ni < 4; ++ni)
      bf4[ni] = *(const bf16x8*)&Bc[boff + ni * 512];
    SP1();
#pragma unroll
    for (int mi = 0; mi < 8; ++mi)
#pragma unroll
      for (int ni = 0; ni < 4; ++ni)
        acc[mi][ni] = __builtin_amdgcn_mfma_f32_16x16x32_bf16(
            af[mi], bf4[ni], acc[mi][ni], 0, 0, 0);
    SP0();
  };

  // ---- prologue: 2-deep prefetch ----
  stage(0, 0);
  stage(1, 1);

  // ---- main loop: depth-2 pipeline, counted vmcnt, 2 barriers/tile ----
#pragma unroll 1
  for (int kt = 0; kt < NTT; ++kt) {
    int b = kt % 3;
    if (kt + 2 < NTT) stage((kt + 2) % 3, kt + 2);
    // retire exactly tile-kt's 6 loads (issued 2 iters ago; zero stall),
    // keep tiles kt+1 / kt+2 in flight.
    if (kt < NTT - 2)       { VMCNT12(); }
    else if (kt == NTT - 2) { VMCNT6(); }
    else                    { VMCNT0(); }
    BARRIER();               // all waves certified tile-kt landed
    compute(&As[b][0], &Bs[b][0]);
    BARRIER();               // reads of buf b done -> safe to overwrite later
  }

  // ---- epilogue (verbatim R9): col = lane&15, row = (lane>>4)*4 + r ----
  int colbase = bn * BN + wn * 64 + lr;
  int rowbase = bm * BM + wm * 128 + g4 * 4;
#pragma unroll
  for (int ni = 0; ni < 4; ++ni) {
    int col = colbase + ni * 16;
    float bv = bias[col];
#pragma unroll
    for (int mi = 0; mi < 8; ++mi) {
#pragma unroll
      for (int r = 0; r < 4; ++r) {
        int row = rowbase + mi * 16 + r;
        out[(size_t)row * K_DIM + col] = acc[mi][ni][r] + bv;
      }
    }
  }
}

// ---------------------------------------------------------------------------
extern "C" void kernel_launch(void* const* d_in, const int* in_sizes, int n_in,
                              void* d_out, int out_size, void* d_ws, size_t ws_size,
                              hipStream_t stream) {
  const float* x     = (const float*)d_in[0];
  const float* core0 = (const float*)d_in[1];
  const float* core1 = (const float*)d_in[2];
  const float* bias  = (const float*)d_in[3];
  float* out = (float*)d_out;

  bf16* Xb = (bf16*)d_ws;
  bf16* GT = (bf16*)((char*)d_ws + (size_t)M_ROWS * K_DIM * sizeof(bf16));

  conv_bf16<<<2048, 256, 0, stream>>>(x, Xb, (M_ROWS * K_DIM) / 4);
  build_gt<<<4096, 256, 0, stream>>>(core0, core1, GT);
  gemm_xg<<<MT2 * NT2, 256, 0, stream>>>(Xb, GT, bias, out);
}